// Round 6
// baseline (4648.508 us; speedup 1.0000x reference)
//
#include <hip/hip_runtime.h>
#include <hip/hip_bf16.h>

typedef __attribute__((ext_vector_type(8))) short short8;
typedef __attribute__((ext_vector_type(4))) float float4v;

#define NN 100000
#define NCH 3125            // NN/32
#define NSLICE 85
#define CPS 37              // chunks per slice (85*37 = 3145 >= 3125)

// workspace layout (float offsets)
#define WS_L      0          // [512][64] f32
#define WS_LR     32768      // [64][512] f32 (transposed L)
#define WS_PSI    65536
#define WS_PINV   66048
#define WS_YY     66560      // diag(Syy)
#define WS_M      67072      // [64][64]
#define WS_IMINV  71168      // [64][64]
#define WS_LT     79360      // BS = beta*Syy [64][512]  (LtermT)
#define WS_SZI    112128     // SzzInv [64][64]
#define WS_SCAL   116224     // 0=A,1=Slog,2=bp
#define WS_BETA   116240     // f32 [64][512] -> ends 149008
#define WS_MPART  149008     // 8*4096 -> ends 181776
#define WS_SYY    181776     // [512][512] f32 -> ends 443920
#define WS_SPART  443920     // 255 * 65536 -> ends 17155600
#define WS_TOTAL_F 17155600ULL

__device__ inline unsigned short f2bf(float f) {
    unsigned int u = __float_as_uint(f);
    u = u + 0x7FFFu + ((u >> 16) & 1u);
    return (unsigned short)(u >> 16);
}

// ---------------- init: L, Lr, Psi ----------------
__global__ void k_init(const float* __restrict__ l1, const float* __restrict__ l2,
                       const float* __restrict__ p1, const float* __restrict__ p2,
                       float* __restrict__ ws) {
    int i = blockIdx.x * 256 + threadIdx.x;
    if (i < 16384) {
        float v = l1[i];
        ws[WS_L + i] = v;
        ws[WS_LR + (i & 63) * 512 + (i >> 6)] = v;
    } else if (i < 32768) {
        float v = l2[i - 16384];
        ws[WS_L + i] = v;
        ws[WS_LR + (i & 63) * 512 + (i >> 6)] = v;
    } else if (i < 33280) {
        int j = i - 32768;
        ws[WS_PSI + j] = (j < 256) ? p1[j] : p2[j - 256];
    }
}

// ---------------- syrk: Syy partials = y y^T over 3 sym tiles x 85 n-slices ----------------
// tile t: 0 = rows[0,256)xcols[0,256), 1 = rows[0,256)xcols[256,512), 2 = rows[256,512)^2
__global__ __launch_bounds__(512, 2) void k_syrk(const float* __restrict__ y, float* __restrict__ ws) {
    __shared__ unsigned short tile[512 * 40];   // [row][40] shorts, data in [0,32)
    const int bid = blockIdx.x;
    const int t3 = bid / NSLICE;
    const int sl = bid - t3 * NSLICE;
    const int ch0 = sl * CPS;
    const int ch1 = (ch0 + CPS < NCH) ? (ch0 + CPS) : NCH;
    const int rbase = (t3 == 2) ? 256 : 0;
    const int nrows = (t3 == 1) ? 512 : 256;
    const int brow  = (t3 == 1) ? 256 : 0;
    const int tt = threadIdx.x;
    const int w = tt >> 6, l = tt & 63, m16 = l & 15, g = l >> 4;
    const int wr = w >> 2, wc = w & 3;     // 2x4 wave grid: 128-row x 64-col per wave

    float4v acc[8][4];
    #pragma unroll
    for (int m = 0; m < 8; m++)
        #pragma unroll
        for (int nq = 0; nq < 4; nq++) acc[m][nq] = (float4v){0.f, 0.f, 0.f, 0.f};

    for (int ch = ch0; ch < ch1; ++ch) {
        __syncthreads();   // previous chunk's frag reads done
        for (int i = tt; i < nrows * 2; i += 512) {
            int row = i >> 1, half = i & 1;
            const float* src = y + (size_t)(rbase + row) * NN + ch * 32 + half * 16;
            float4 f0 = *(const float4*)src;
            float4 f1 = *(const float4*)(src + 4);
            float4 f2 = *(const float4*)(src + 8);
            float4 f3 = *(const float4*)(src + 12);
            short8 h0, h1;
            h0[0] = (short)f2bf(f0.x); h0[1] = (short)f2bf(f0.y);
            h0[2] = (short)f2bf(f0.z); h0[3] = (short)f2bf(f0.w);
            h0[4] = (short)f2bf(f1.x); h0[5] = (short)f2bf(f1.y);
            h0[6] = (short)f2bf(f1.z); h0[7] = (short)f2bf(f1.w);
            h1[0] = (short)f2bf(f2.x); h1[1] = (short)f2bf(f2.y);
            h1[2] = (short)f2bf(f2.z); h1[3] = (short)f2bf(f2.w);
            h1[4] = (short)f2bf(f3.x); h1[5] = (short)f2bf(f3.y);
            h1[6] = (short)f2bf(f3.z); h1[7] = (short)f2bf(f3.w);
            *(short8*)&tile[row * 40 + half * 16] = h0;
            *(short8*)&tile[row * 40 + half * 16 + 8] = h1;
        }
        __syncthreads();
        short8 af[8], bf[4];
        #pragma unroll
        for (int m = 0; m < 8; m++)
            af[m] = *(const short8*)&tile[(128 * wr + 16 * m + m16) * 40 + 8 * g];
        #pragma unroll
        for (int nq = 0; nq < 4; nq++)
            bf[nq] = *(const short8*)&tile[(brow + 64 * wc + 16 * nq + m16) * 40 + 8 * g];
        #pragma unroll
        for (int m = 0; m < 8; m++)
            #pragma unroll
            for (int nq = 0; nq < 4; nq++)
                acc[m][nq] = __builtin_amdgcn_mfma_f32_16x16x32_bf16(af[m], bf[nq], acc[m][nq], 0, 0, 0);
    }
    float* part = ws + WS_SPART + (size_t)bid * 65536;
    #pragma unroll
    for (int m = 0; m < 8; m++)
        #pragma unroll
        for (int nq = 0; nq < 4; nq++)
            #pragma unroll
            for (int r = 0; r < 4; r++)
                part[(128 * wr + 16 * m + 4 * g + r) * 256 + 64 * wc + 16 * nq + m16] = acc[m][nq][r];
}

// ---------------- reduce syrk partials -> Syy full [512][512], yy diag ----------------
__global__ __launch_bounds__(256) void k_syy_reduce(float* __restrict__ ws) {
    int o = blockIdx.x * 256 + threadIdx.x;   // 0..262143
    int i = o >> 9, j = o & 511;
    int t3, li, lj;
    if (i < 256) {
        if (j < 256) { t3 = 0; li = i; lj = j; }
        else         { t3 = 1; li = i; lj = j - 256; }
    } else {
        if (j >= 256) { t3 = 2; li = i - 256; lj = j - 256; }
        else          { t3 = 1; li = j; lj = i - 256; }   // transpose of upper-right
    }
    const float* base = ws + WS_SPART + (size_t)t3 * NSLICE * 65536 + li * 256 + lj;
    float s = 0.f;
    #pragma unroll 5
    for (int sl = 0; sl < NSLICE; sl++) s += base[(size_t)sl * 65536];
    ws[WS_SYY + o] = s;
    if (i == j) ws[WS_YY + i] = s;
}

// ---------------- Gauss-Jordan 64x64, 512 threads ----------------
__device__ inline void gj64_512(float (*aug)[129], float* prow, float* fac, int t) {
    for (int piv = 0; piv < 64; piv++) {
        if (t < 128) prow[t] = aug[piv][t];
        else if (t < 192) fac[t - 128] = aug[t - 128][piv];
        __syncthreads();
        float ip = 1.f / prow[piv];
        #pragma unroll
        for (int q = 0; q < 16; q++) {
            int o = t + q * 512;
            int r = o >> 7, c = o & 127;
            float pv = prow[c] * ip;
            float v = aug[r][c];
            aug[r][c] = (r == piv) ? pv : v - fac[r] * pv;
        }
        __syncthreads();
    }
}

// ---------------- shared: per-64p-block M partial from g = sqrt(pi)*L rows ----------------
__device__ inline void partial_M(const float (*g)[68], int t, float* __restrict__ dst) {
    const int i2 = t & 63, w8 = t >> 6;
    float macc[8] = {0.f, 0.f, 0.f, 0.f, 0.f, 0.f, 0.f, 0.f};
    #pragma unroll 8
    for (int p = 0; p < 64; p++) {
        float a = g[p][i2];
        float4 b0 = *(const float4*)&g[p][8 * w8];
        float4 b1 = *(const float4*)&g[p][8 * w8 + 4];
        macc[0] = fmaf(a, b0.x, macc[0]); macc[1] = fmaf(a, b0.y, macc[1]);
        macc[2] = fmaf(a, b0.z, macc[2]); macc[3] = fmaf(a, b0.w, macc[3]);
        macc[4] = fmaf(a, b1.x, macc[4]); macc[5] = fmaf(a, b1.y, macc[5]);
        macc[6] = fmaf(a, b1.z, macc[6]); macc[7] = fmaf(a, b1.w, macc[7]);
    }
    float4 s0 = make_float4(macc[0], macc[1], macc[2], macc[3]);
    float4 s1 = make_float4(macc[4], macc[5], macc[6], macc[7]);
    *(float4*)&dst[i2 * 64 + 8 * w8] = s0;
    *(float4*)&dst[i2 * 64 + 8 * w8 + 4] = s1;
}

// ---------------- m0: seed M-partials from initial params ----------------
__global__ __launch_bounds__(512) void k_m0(float* __restrict__ ws) {
    __shared__ float g[64][68];
    const int t = threadIdx.x, b = blockIdx.x;
    const int pl = t >> 3, oct = t & 7;
    const int p = 64 * b + pl;
    float rs = rsqrtf(fmaxf(ws[WS_PSI + p], 1e-8f));
    float4 v0 = *(const float4*)&ws[WS_L + p * 64 + oct * 8];
    float4 v1 = *(const float4*)&ws[WS_L + p * 64 + oct * 8 + 4];
    g[pl][oct * 8 + 0] = rs * v0.x; g[pl][oct * 8 + 1] = rs * v0.y;
    g[pl][oct * 8 + 2] = rs * v0.z; g[pl][oct * 8 + 3] = rs * v0.w;
    g[pl][oct * 8 + 4] = rs * v1.x; g[pl][oct * 8 + 5] = rs * v1.y;
    g[pl][oct * 8 + 6] = rs * v1.z; g[pl][oct * 8 + 7] = rs * v1.w;
    __syncthreads();
    partial_M(g, t, ws + WS_MPART + b * 4096);
}

// ---------------- pre: pi, A, Slog, M-sum, (I+M)^-1, beta f32 ----------------
__global__ __launch_bounds__(512) void k_pre(float* __restrict__ ws) {
    __shared__ float aug[64][129];
    __shared__ float prow[128];
    __shared__ float fac[64];
    __shared__ float2 red[512];
    const int t = threadIdx.x;

    float pv = ws[WS_PSI + t];
    float iv = 1.f / pv;
    ws[WS_PINV + t] = iv;
    if (t == 0) ws[WS_SCAL + 2] = 0.f;
    red[t] = make_float2(0.5f * iv * ws[WS_YY + t], logf(pv));

    // M = sum of 8 partials; build aug
    #pragma unroll
    for (int q = 0; q < 8; q++) {
        int o = t + 512 * q;
        float m = 0.f;
        #pragma unroll
        for (int b = 0; b < 8; b++) m += ws[WS_MPART + b * 4096 + o];
        int i = o >> 6, j = o & 63;
        ws[WS_M + o] = m;
        aug[i][j] = m + ((i == j) ? 1.f : 0.f);
        aug[i][64 + j] = (i == j) ? 1.f : 0.f;
    }
    __syncthreads();
    for (int st = 256; st > 0; st >>= 1) {
        if (t < st) { red[t].x += red[t + st].x; red[t].y += red[t + st].y; }
        __syncthreads();
    }
    if (t == 0) { ws[WS_SCAL + 0] = red[0].x; ws[WS_SCAL + 1] = red[0].y; }

    gj64_512(aug, prow, fac, t);
    #pragma unroll
    for (int q = 0; q < 8; q++) {
        int o = t + 512 * q;
        ws[WS_IMINV + o] = aug[o >> 6][64 + (o & 63)];
    }
    // no barrier needed: beta phase reads aug[][64+] which is final

    // beta[k][p=t] = pinv[p] * sum_j IMinv[k][j] * L[p][j]
    float lrow[64];
    #pragma unroll
    for (int j4 = 0; j4 < 16; j4++) {
        float4 v = *(const float4*)&ws[WS_L + t * 64 + j4 * 4];
        lrow[4 * j4 + 0] = v.x; lrow[4 * j4 + 1] = v.y;
        lrow[4 * j4 + 2] = v.z; lrow[4 * j4 + 3] = v.w;
    }
    for (int k = 0; k < 64; k++) {
        float s = 0.f;
        #pragma unroll
        for (int j = 0; j < 64; j++) s = fmaf(aug[k][64 + j], lrow[j], s);
        ws[WS_BETA + k * 512 + t] = s * iv;
    }
}

// ---------------- mid: BS = beta * Syy  [64][512], bp partial ----------------
__global__ __launch_bounds__(512) void k_mid1(float* __restrict__ ws) {
    __shared__ float rsum[512];
    const int b = blockIdx.x, tt = threadIdx.x;
    const int k = tt >> 3, poct = tt & 7;
    const int p0 = 64 * b + 8 * poct;
    float a0 = 0.f, a1 = 0.f, a2 = 0.f, a3 = 0.f, a4 = 0.f, a5 = 0.f, a6 = 0.f, a7 = 0.f;
    const float* brow = ws + WS_BETA + k * 512;
    #pragma unroll 4
    for (int q = 0; q < 512; q++) {
        float bq = brow[q];
        float4 s0 = *(const float4*)&ws[WS_SYY + q * 512 + p0];
        float4 s1 = *(const float4*)&ws[WS_SYY + q * 512 + p0 + 4];
        a0 = fmaf(bq, s0.x, a0); a1 = fmaf(bq, s0.y, a1);
        a2 = fmaf(bq, s0.z, a2); a3 = fmaf(bq, s0.w, a3);
        a4 = fmaf(bq, s1.x, a4); a5 = fmaf(bq, s1.y, a5);
        a6 = fmaf(bq, s1.z, a6); a7 = fmaf(bq, s1.w, a7);
    }
    *(float4*)&ws[WS_LT + k * 512 + p0] = make_float4(a0, a1, a2, a3);
    *(float4*)&ws[WS_LT + k * 512 + p0 + 4] = make_float4(a4, a5, a6, a7);
    // bp = sum pinv[p] * L[p][k] * BS[k][p]
    float bp = 0.f;
    float4 pi0 = *(const float4*)&ws[WS_PINV + p0];
    float4 pi1 = *(const float4*)&ws[WS_PINV + p0 + 4];
    float4 lr0 = *(const float4*)&ws[WS_LR + k * 512 + p0];
    float4 lr1 = *(const float4*)&ws[WS_LR + k * 512 + p0 + 4];
    bp = fmaf(pi0.x * lr0.x, a0, bp); bp = fmaf(pi0.y * lr0.y, a1, bp);
    bp = fmaf(pi0.z * lr0.z, a2, bp); bp = fmaf(pi0.w * lr0.w, a3, bp);
    bp = fmaf(pi1.x * lr1.x, a4, bp); bp = fmaf(pi1.y * lr1.y, a5, bp);
    bp = fmaf(pi1.z * lr1.z, a6, bp); bp = fmaf(pi1.w * lr1.w, a7, bp);
    rsum[tt] = bp;
    __syncthreads();
    for (int st = 256; st > 0; st >>= 1) {
        if (tt < st) rsum[tt] += rsum[tt + st];
        __syncthreads();
    }
    if (tt == 0) atomicAdd(ws + WS_SCAL + 2, rsum[0]);
}

// ---------------- post: Czz, cp, nll, Szz^-1 ----------------
__global__ __launch_bounds__(512) void k_post(float* __restrict__ ws, float* __restrict__ dout, int pass) {
    __shared__ float aug[64][129];
    __shared__ float czz[64][65];
    __shared__ float prow[128];
    __shared__ float fac[64];
    const int t = threadIdx.x;
    const int k = t >> 3, koct = t & 7;

    // Czz[k][k'] = sum_p BS[k][p] * beta[k'][p]
    float a8[8] = {0.f, 0.f, 0.f, 0.f, 0.f, 0.f, 0.f, 0.f};
    #pragma unroll 4
    for (int p = 0; p < 512; p++) {
        float bs = ws[WS_LT + k * 512 + p];
        #pragma unroll
        for (int i = 0; i < 8; i++)
            a8[i] = fmaf(bs, ws[WS_BETA + (8 * koct + i) * 512 + p], a8[i]);
    }
    #pragma unroll
    for (int i = 0; i < 8; i++) czz[k][8 * koct + i] = a8[i];
    // cp partial: sum M .* (n*IMinv + Czz)
    float cp = 0.f;
    #pragma unroll
    for (int i = 0; i < 8; i++) {
        int o = k * 64 + 8 * koct + i;
        cp = fmaf(ws[WS_M + o], (float)NN * ws[WS_IMINV + o] + a8[i], cp);
    }
    prow[0] = 0.f;   // reuse as scratch? no -- use fac region via separate reduce below
    __shared__ float rsum[512];
    rsum[t] = cp;
    __syncthreads();
    for (int st = 256; st > 0; st >>= 1) {
        if (t < st) rsum[t] += rsum[t + st];
        __syncthreads();
    }
    if (t == 0 && pass >= 1) {
        float A = ws[WS_SCAL + 0], Slog = ws[WS_SCAL + 1], bp = ws[WS_SCAL + 2];
        dout[33280 + pass - 1] = A - bp + 0.5f * rsum[0] + 0.5f * (float)NN * Slog;
    }
    if (pass == 8) return;

    #pragma unroll
    for (int q = 0; q < 8; q++) {
        int o = t + 512 * q;
        int i = o >> 6, j = o & 63;
        aug[i][j] = (float)NN * ws[WS_IMINV + o] + czz[i][j];
        aug[i][64 + j] = (i == j) ? 1.f : 0.f;
    }
    __syncthreads();
    gj64_512(aug, prow, fac, t);
    #pragma unroll
    for (int q = 0; q < 8; q++) {
        int o = t + 512 * q;
        ws[WS_SZI + o] = aug[o >> 6][64 + (o & 63)];
    }
}

// ---------------- upd: Lambda_new, Psi_new, L/Lr/Psi update, next M partials ----------------
__global__ __launch_bounds__(512) void k_upd(float* __restrict__ ws, float* __restrict__ dout, int pass) {
    __shared__ float szi[64][68];
    __shared__ float lt[64][66];
    const int t = threadIdx.x, b = blockIdx.x;
    const int p0 = 64 * b;
    const int pl = t >> 3, oct = t & 7;
    const int p = p0 + pl;

    if (pass == 8) {
        float4 v0 = *(const float4*)&ws[WS_L + p * 64 + oct * 8];
        float4 v1 = *(const float4*)&ws[WS_L + p * 64 + oct * 8 + 4];
        *(float4*)&dout[p * 64 + oct * 8] = v0;
        *(float4*)&dout[p * 64 + oct * 8 + 4] = v1;
        if (oct == 0) dout[32768 + p] = ws[WS_PSI + p];
        return;
    }

    #pragma unroll
    for (int q = 0; q < 8; q++) { int o = t + 512 * q; szi[o >> 6][o & 63] = ws[WS_SZI + o]; }
    #pragma unroll
    for (int q = 0; q < 8; q++) { int o = t + 512 * q; lt[o >> 6][o & 63] = ws[WS_LT + (o >> 6) * 512 + p0 + (o & 63)]; }
    __syncthreads();

    float acc[8] = {0.f, 0.f, 0.f, 0.f, 0.f, 0.f, 0.f, 0.f};
    #pragma unroll
    for (int j = 0; j < 64; j++) {
        float ltv = lt[j][pl];
        float4 s0 = *(const float4*)&szi[j][oct * 8];
        float4 s1 = *(const float4*)&szi[j][oct * 8 + 4];
        acc[0] = fmaf(ltv, s0.x, acc[0]); acc[1] = fmaf(ltv, s0.y, acc[1]);
        acc[2] = fmaf(ltv, s0.z, acc[2]); acc[3] = fmaf(ltv, s0.w, acc[3]);
        acc[4] = fmaf(ltv, s1.x, acc[4]); acc[5] = fmaf(ltv, s1.y, acc[5]);
        acc[6] = fmaf(ltv, s1.z, acc[6]); acc[7] = fmaf(ltv, s1.w, acc[7]);
    }
    float psum = 0.f;
    #pragma unroll
    for (int i = 0; i < 8; i++) psum = fmaf(acc[i], lt[oct * 8 + i][pl], psum);
    psum += __shfl_xor(psum, 1);
    psum += __shfl_xor(psum, 2);
    psum += __shfl_xor(psum, 4);
    float psin = (ws[WS_YY + p] - psum) * (1.f / (float)NN);

    float4 a0 = make_float4(acc[0], acc[1], acc[2], acc[3]);
    float4 a1 = make_float4(acc[4], acc[5], acc[6], acc[7]);
    *(float4*)&ws[WS_L + p * 64 + oct * 8] = a0;
    *(float4*)&ws[WS_L + p * 64 + oct * 8 + 4] = a1;
    #pragma unroll
    for (int i = 0; i < 8; i++) ws[WS_LR + (oct * 8 + i) * 512 + p] = acc[i];
    if (oct == 0) ws[WS_PSI + p] = psin;

    float rs = rsqrtf(fmaxf(psin, 1e-8f));
    __syncthreads();
    #pragma unroll
    for (int i = 0; i < 8; i++) szi[pl][oct * 8 + i] = rs * acc[i];
    __syncthreads();
    partial_M(szi, t, ws + WS_MPART + b * 4096);
}

extern "C" void kernel_launch(void* const* d_in, const int* in_sizes, int n_in,
                              void* d_out, int out_size, void* d_ws, size_t ws_size,
                              hipStream_t stream) {
    const float* y  = (const float*)d_in[0];
    const float* l1 = (const float*)d_in[1];
    const float* l2 = (const float*)d_in[2];
    const float* p1 = (const float*)d_in[3];
    const float* p2 = (const float*)d_in[4];
    float* out = (float*)d_out;
    float* ws  = (float*)d_ws;

    if (ws_size < WS_TOTAL_F * sizeof(float)) return;

    k_init<<<130, 256, 0, stream>>>(l1, l2, p1, p2, ws);
    k_syrk<<<3 * NSLICE, 512, 0, stream>>>(y, ws);
    k_syy_reduce<<<1024, 256, 0, stream>>>(ws);
    k_m0<<<8, 512, 0, stream>>>(ws);
    for (int pass = 0; pass <= 8; pass++) {
        k_pre<<<1, 512, 0, stream>>>(ws);
        k_mid1<<<8, 512, 0, stream>>>(ws);
        k_post<<<1, 512, 0, stream>>>(ws, out, pass);
        k_upd<<<8, 512, 0, stream>>>(ws, out, pass);
    }
}

// Round 7
// 2696.946 us; speedup vs baseline: 1.7236x; 1.7236x over previous
//
#include <hip/hip_runtime.h>
#include <hip/hip_bf16.h>

typedef __attribute__((ext_vector_type(8))) short short8;
typedef __attribute__((ext_vector_type(4))) float float4v;

#define NN 100000
#define NCH 3125            // NN/32
#define NSLICE 85
#define CPS 37              // chunks per slice (85*37 = 3145 >= 3125)

// workspace layout (float offsets)
#define WS_L      0          // [512][64] f32
#define WS_LR     32768      // [64][512] f32 (transposed L)
#define WS_PSI    65536
#define WS_PINV   66048
#define WS_YY     66560      // diag(Syy)
#define WS_M      67072      // [64][64]
#define WS_IMINV  71168      // [64][64]
#define WS_LT     79360      // BS = beta*Syy [64][512]  (LtermT)
#define WS_SZI    112128     // SzzInv [64][64]
#define WS_SCAL   116224     // 0=A,1=Slog,2=bp
#define WS_BETA   116240     // f32 [64][512] -> ends 149008
#define WS_MPART  149008     // 8*4096 -> ends 181776
#define WS_CPART  181776     // 8*4096 Czz partials -> ends 214544
#define WS_SYY    214544     // [512][512] f32 -> ends 476688
#define WS_SPART  476688     // 255 * 65536 -> ends 17188368
#define WS_TOTAL_F 17188368ULL

__device__ inline unsigned short f2bf(float f) {
    unsigned int u = __float_as_uint(f);
    u = u + 0x7FFFu + ((u >> 16) & 1u);
    return (unsigned short)(u >> 16);
}

// ---------------- init: L, Lr, Psi ----------------
__global__ void k_init(const float* __restrict__ l1, const float* __restrict__ l2,
                       const float* __restrict__ p1, const float* __restrict__ p2,
                       float* __restrict__ ws) {
    int i = blockIdx.x * 256 + threadIdx.x;
    if (i < 16384) {
        float v = l1[i];
        ws[WS_L + i] = v;
        ws[WS_LR + (i & 63) * 512 + (i >> 6)] = v;
    } else if (i < 32768) {
        float v = l2[i - 16384];
        ws[WS_L + i] = v;
        ws[WS_LR + (i & 63) * 512 + (i >> 6)] = v;
    } else if (i < 33280) {
        int j = i - 32768;
        ws[WS_PSI + j] = (j < 256) ? p1[j] : p2[j - 256];
    }
}

// ---------------- syrk: Syy partials = y y^T over 3 sym tiles x 85 n-slices ----------------
__global__ __launch_bounds__(512, 2) void k_syrk(const float* __restrict__ y, float* __restrict__ ws) {
    __shared__ unsigned short tile[512 * 40];   // [row][40] shorts, data in [0,32)
    const int bid = blockIdx.x;
    const int t3 = bid / NSLICE;
    const int sl = bid - t3 * NSLICE;
    const int ch0 = sl * CPS;
    const int ch1 = (ch0 + CPS < NCH) ? (ch0 + CPS) : NCH;
    const int rbase = (t3 == 2) ? 256 : 0;
    const int nrows = (t3 == 1) ? 512 : 256;
    const int brow  = (t3 == 1) ? 256 : 0;
    const int tt = threadIdx.x;
    const int w = tt >> 6, l = tt & 63, m16 = l & 15, g = l >> 4;
    const int wr = w >> 2, wc = w & 3;     // 2x4 wave grid: 128-row x 64-col per wave

    float4v acc[8][4];
    #pragma unroll
    for (int m = 0; m < 8; m++)
        #pragma unroll
        for (int nq = 0; nq < 4; nq++) acc[m][nq] = (float4v){0.f, 0.f, 0.f, 0.f};

    for (int ch = ch0; ch < ch1; ++ch) {
        __syncthreads();   // previous chunk's frag reads done
        for (int i = tt; i < nrows * 2; i += 512) {
            int row = i >> 1, half = i & 1;
            const float* src = y + (size_t)(rbase + row) * NN + ch * 32 + half * 16;
            float4 f0 = *(const float4*)src;
            float4 f1 = *(const float4*)(src + 4);
            float4 f2 = *(const float4*)(src + 8);
            float4 f3 = *(const float4*)(src + 12);
            short8 h0, h1;
            h0[0] = (short)f2bf(f0.x); h0[1] = (short)f2bf(f0.y);
            h0[2] = (short)f2bf(f0.z); h0[3] = (short)f2bf(f0.w);
            h0[4] = (short)f2bf(f1.x); h0[5] = (short)f2bf(f1.y);
            h0[6] = (short)f2bf(f1.z); h0[7] = (short)f2bf(f1.w);
            h1[0] = (short)f2bf(f2.x); h1[1] = (short)f2bf(f2.y);
            h1[2] = (short)f2bf(f2.z); h1[3] = (short)f2bf(f2.w);
            h1[4] = (short)f2bf(f3.x); h1[5] = (short)f2bf(f3.y);
            h1[6] = (short)f2bf(f3.z); h1[7] = (short)f2bf(f3.w);
            *(short8*)&tile[row * 40 + half * 16] = h0;
            *(short8*)&tile[row * 40 + half * 16 + 8] = h1;
        }
        __syncthreads();
        short8 af[8], bf[4];
        #pragma unroll
        for (int m = 0; m < 8; m++)
            af[m] = *(const short8*)&tile[(128 * wr + 16 * m + m16) * 40 + 8 * g];
        #pragma unroll
        for (int nq = 0; nq < 4; nq++)
            bf[nq] = *(const short8*)&tile[(brow + 64 * wc + 16 * nq + m16) * 40 + 8 * g];
        #pragma unroll
        for (int m = 0; m < 8; m++)
            #pragma unroll
            for (int nq = 0; nq < 4; nq++)
                acc[m][nq] = __builtin_amdgcn_mfma_f32_16x16x32_bf16(af[m], bf[nq], acc[m][nq], 0, 0, 0);
    }
    float* part = ws + WS_SPART + (size_t)bid * 65536;
    #pragma unroll
    for (int m = 0; m < 8; m++)
        #pragma unroll
        for (int nq = 0; nq < 4; nq++)
            #pragma unroll
            for (int r = 0; r < 4; r++)
                part[(128 * wr + 16 * m + 4 * g + r) * 256 + 64 * wc + 16 * nq + m16] = acc[m][nq][r];
}

// ---------------- reduce syrk partials -> Syy full [512][512], yy diag ----------------
__global__ __launch_bounds__(256) void k_syy_reduce(float* __restrict__ ws) {
    int o = blockIdx.x * 256 + threadIdx.x;   // 0..262143
    int i = o >> 9, j = o & 511;
    int t3, li, lj;
    if (i < 256) {
        if (j < 256) { t3 = 0; li = i; lj = j; }
        else         { t3 = 1; li = i; lj = j - 256; }
    } else {
        if (j >= 256) { t3 = 2; li = i - 256; lj = j - 256; }
        else          { t3 = 1; li = j; lj = i - 256; }   // transpose of upper-right
    }
    const float* base = ws + WS_SPART + (size_t)t3 * NSLICE * 65536 + li * 256 + lj;
    float s = 0.f;
    #pragma unroll 5
    for (int sl = 0; sl < NSLICE; sl++) s += base[(size_t)sl * 65536];
    ws[WS_SYY + o] = s;
    if (i == j) ws[WS_YY + i] = s;
}

// ---------------- Gauss-Jordan 64x64, 512 threads ----------------
__device__ inline void gj64_512(float (*aug)[129], float* prow, float* fac, int t) {
    for (int piv = 0; piv < 64; piv++) {
        if (t < 128) prow[t] = aug[piv][t];
        else if (t < 192) fac[t - 128] = aug[t - 128][piv];
        __syncthreads();
        float ip = 1.f / prow[piv];
        #pragma unroll
        for (int q = 0; q < 16; q++) {
            int o = t + q * 512;
            int r = o >> 7, c = o & 127;
            float pv = prow[c] * ip;
            float v = aug[r][c];
            aug[r][c] = (r == piv) ? pv : v - fac[r] * pv;
        }
        __syncthreads();
    }
}

// ---------------- shared: per-64p-block M partial from g = sqrt(pi)*L rows ----------------
__device__ inline void partial_M(const float (*g)[68], int t, float* __restrict__ dst) {
    const int i2 = t & 63, w8 = t >> 6;
    float macc[8] = {0.f, 0.f, 0.f, 0.f, 0.f, 0.f, 0.f, 0.f};
    #pragma unroll 8
    for (int p = 0; p < 64; p++) {
        float a = g[p][i2];
        float4 b0 = *(const float4*)&g[p][8 * w8];
        float4 b1 = *(const float4*)&g[p][8 * w8 + 4];
        macc[0] = fmaf(a, b0.x, macc[0]); macc[1] = fmaf(a, b0.y, macc[1]);
        macc[2] = fmaf(a, b0.z, macc[2]); macc[3] = fmaf(a, b0.w, macc[3]);
        macc[4] = fmaf(a, b1.x, macc[4]); macc[5] = fmaf(a, b1.y, macc[5]);
        macc[6] = fmaf(a, b1.z, macc[6]); macc[7] = fmaf(a, b1.w, macc[7]);
    }
    float4 s0 = make_float4(macc[0], macc[1], macc[2], macc[3]);
    float4 s1 = make_float4(macc[4], macc[5], macc[6], macc[7]);
    *(float4*)&dst[i2 * 64 + 8 * w8] = s0;
    *(float4*)&dst[i2 * 64 + 8 * w8 + 4] = s1;
}

// ---------------- m0: seed M-partials from initial params ----------------
__global__ __launch_bounds__(512) void k_m0(float* __restrict__ ws) {
    __shared__ float g[64][68];
    const int t = threadIdx.x, b = blockIdx.x;
    const int pl = t >> 3, oct = t & 7;
    const int p = 64 * b + pl;
    float rs = rsqrtf(fmaxf(ws[WS_PSI + p], 1e-8f));
    float4 v0 = *(const float4*)&ws[WS_L + p * 64 + oct * 8];
    float4 v1 = *(const float4*)&ws[WS_L + p * 64 + oct * 8 + 4];
    g[pl][oct * 8 + 0] = rs * v0.x; g[pl][oct * 8 + 1] = rs * v0.y;
    g[pl][oct * 8 + 2] = rs * v0.z; g[pl][oct * 8 + 3] = rs * v0.w;
    g[pl][oct * 8 + 4] = rs * v1.x; g[pl][oct * 8 + 5] = rs * v1.y;
    g[pl][oct * 8 + 6] = rs * v1.z; g[pl][oct * 8 + 7] = rs * v1.w;
    __syncthreads();
    partial_M(g, t, ws + WS_MPART + b * 4096);
}

// ---------------- pre: pi, A, Slog, M-sum, (I+M)^-1, beta f32 ----------------
__global__ __launch_bounds__(512) void k_pre(float* __restrict__ ws) {
    __shared__ float aug[64][129];
    __shared__ float prow[128];
    __shared__ float fac[64];
    __shared__ float2 red[512];
    const int t = threadIdx.x;

    float pv = ws[WS_PSI + t];
    float iv = 1.f / pv;
    ws[WS_PINV + t] = iv;
    if (t == 0) ws[WS_SCAL + 2] = 0.f;
    red[t] = make_float2(0.5f * iv * ws[WS_YY + t], logf(pv));

    // M = sum of 8 partials; build aug
    #pragma unroll
    for (int q = 0; q < 8; q++) {
        int o = t + 512 * q;
        float m = 0.f;
        #pragma unroll
        for (int b = 0; b < 8; b++) m += ws[WS_MPART + b * 4096 + o];
        int i = o >> 6, j = o & 63;
        ws[WS_M + o] = m;
        aug[i][j] = m + ((i == j) ? 1.f : 0.f);
        aug[i][64 + j] = (i == j) ? 1.f : 0.f;
    }
    __syncthreads();
    for (int st = 256; st > 0; st >>= 1) {
        if (t < st) { red[t].x += red[t + st].x; red[t].y += red[t + st].y; }
        __syncthreads();
    }
    if (t == 0) { ws[WS_SCAL + 0] = red[0].x; ws[WS_SCAL + 1] = red[0].y; }

    gj64_512(aug, prow, fac, t);
    #pragma unroll
    for (int q = 0; q < 8; q++) {
        int o = t + 512 * q;
        ws[WS_IMINV + o] = aug[o >> 6][64 + (o & 63)];
    }

    // beta[k][p=t] = pinv[p] * sum_j IMinv[k][j] * L[p][j]
    float lrow[64];
    #pragma unroll
    for (int j4 = 0; j4 < 16; j4++) {
        float4 v = *(const float4*)&ws[WS_L + t * 64 + j4 * 4];
        lrow[4 * j4 + 0] = v.x; lrow[4 * j4 + 1] = v.y;
        lrow[4 * j4 + 2] = v.z; lrow[4 * j4 + 3] = v.w;
    }
    for (int k = 0; k < 64; k++) {
        float s = 0.f;
        #pragma unroll
        for (int j = 0; j < 64; j++) s = fmaf(aug[k][64 + j], lrow[j], s);
        ws[WS_BETA + k * 512 + t] = s * iv;
    }
}

// ---------------- mid: BS = beta * Syy  [64][512], bp partial, Czz partial ----------------
__global__ __launch_bounds__(512) void k_mid1(float* __restrict__ ws) {
    __shared__ float rsum[512];
    __shared__ float BSs[64][65];
    __shared__ float betas[64][65];
    const int b = blockIdx.x, tt = threadIdx.x;
    const int k = tt >> 3, poct = tt & 7;
    const int p0 = 64 * b + 8 * poct;
    float a0 = 0.f, a1 = 0.f, a2 = 0.f, a3 = 0.f, a4 = 0.f, a5 = 0.f, a6 = 0.f, a7 = 0.f;
    const float* brow = ws + WS_BETA + k * 512;
    #pragma unroll 4
    for (int q = 0; q < 512; q++) {
        float bq = brow[q];
        float4 s0 = *(const float4*)&ws[WS_SYY + q * 512 + p0];
        float4 s1 = *(const float4*)&ws[WS_SYY + q * 512 + p0 + 4];
        a0 = fmaf(bq, s0.x, a0); a1 = fmaf(bq, s0.y, a1);
        a2 = fmaf(bq, s0.z, a2); a3 = fmaf(bq, s0.w, a3);
        a4 = fmaf(bq, s1.x, a4); a5 = fmaf(bq, s1.y, a5);
        a6 = fmaf(bq, s1.z, a6); a7 = fmaf(bq, s1.w, a7);
    }
    *(float4*)&ws[WS_LT + k * 512 + p0] = make_float4(a0, a1, a2, a3);
    *(float4*)&ws[WS_LT + k * 512 + p0 + 4] = make_float4(a4, a5, a6, a7);
    // stage BS block into LDS
    *(float4*)&BSs[k][8 * poct] = make_float4(a0, a1, a2, a3);
    *(float4*)&BSs[k][8 * poct + 4] = make_float4(a4, a5, a6, a7);
    // stage beta block [64][64] into LDS (coalesced)
    #pragma unroll
    for (int q = 0; q < 8; q++) {
        int o = tt + 512 * q;
        betas[o >> 6][o & 63] = ws[WS_BETA + (o >> 6) * 512 + 64 * b + (o & 63)];
    }
    // bp = sum pinv[p] * L[p][k] * BS[k][p]
    float bp = 0.f;
    {
        float4 pi0 = *(const float4*)&ws[WS_PINV + p0];
        float4 pi1 = *(const float4*)&ws[WS_PINV + p0 + 4];
        float4 lr0 = *(const float4*)&ws[WS_LR + k * 512 + p0];
        float4 lr1 = *(const float4*)&ws[WS_LR + k * 512 + p0 + 4];
        bp = fmaf(pi0.x * lr0.x, a0, bp); bp = fmaf(pi0.y * lr0.y, a1, bp);
        bp = fmaf(pi0.z * lr0.z, a2, bp); bp = fmaf(pi0.w * lr0.w, a3, bp);
        bp = fmaf(pi1.x * lr1.x, a4, bp); bp = fmaf(pi1.y * lr1.y, a5, bp);
        bp = fmaf(pi1.z * lr1.z, a6, bp); bp = fmaf(pi1.w * lr1.w, a7, bp);
    }
    rsum[tt] = bp;
    __syncthreads();
    for (int st = 256; st > 0; st >>= 1) {
        if (tt < st) rsum[tt] += rsum[tt + st];
        __syncthreads();
    }
    if (tt == 0) atomicAdd(ws + WS_SCAL + 2, rsum[0]);
    // Czz partial for this p-block: czz_b[k][k2] = sum_p BSs[k][p] * betas[k2][p]
    float c8[8] = {0.f, 0.f, 0.f, 0.f, 0.f, 0.f, 0.f, 0.f};
    #pragma unroll 8
    for (int p = 0; p < 64; p++) {
        float bs = BSs[k][p];
        #pragma unroll
        for (int i = 0; i < 8; i++) c8[i] = fmaf(bs, betas[8 * poct + i][p], c8[i]);
    }
    float* cdst = ws + WS_CPART + b * 4096 + k * 64 + 8 * poct;
    *(float4*)cdst = make_float4(c8[0], c8[1], c8[2], c8[3]);
    *(float4*)(cdst + 4) = make_float4(c8[4], c8[5], c8[6], c8[7]);
}

// ---------------- post: Czz sum, cp, nll, Szz^-1 ----------------
__global__ __launch_bounds__(512) void k_post(float* __restrict__ ws, float* __restrict__ dout, int pass) {
    __shared__ float aug[64][129];
    __shared__ float prow[128];
    __shared__ float fac[64];
    __shared__ float rsum[512];
    const int t = threadIdx.x;

    // Czz = sum of 8 partials (coalesced); cp partial on the fly
    float cz[8];
    float cp = 0.f;
    #pragma unroll
    for (int q = 0; q < 8; q++) {
        int o = t + 512 * q;
        float s = 0.f;
        #pragma unroll
        for (int b = 0; b < 8; b++) s += ws[WS_CPART + b * 4096 + o];
        cz[q] = s;
        cp = fmaf(ws[WS_M + o], (float)NN * ws[WS_IMINV + o] + s, cp);
    }
    rsum[t] = cp;
    __syncthreads();
    for (int st = 256; st > 0; st >>= 1) {
        if (t < st) rsum[t] += rsum[t + st];
        __syncthreads();
    }
    if (t == 0 && pass >= 1) {
        float A = ws[WS_SCAL + 0], Slog = ws[WS_SCAL + 1], bp = ws[WS_SCAL + 2];
        dout[33280 + pass - 1] = A - bp + 0.5f * rsum[0] + 0.5f * (float)NN * Slog;
    }
    if (pass == 8) return;

    #pragma unroll
    for (int q = 0; q < 8; q++) {
        int o = t + 512 * q;
        int i = o >> 6, j = o & 63;
        aug[i][j] = (float)NN * ws[WS_IMINV + o] + cz[q];
        aug[i][64 + j] = (i == j) ? 1.f : 0.f;
    }
    __syncthreads();
    gj64_512(aug, prow, fac, t);
    #pragma unroll
    for (int q = 0; q < 8; q++) {
        int o = t + 512 * q;
        ws[WS_SZI + o] = aug[o >> 6][64 + (o & 63)];
    }
}

// ---------------- upd: Lambda_new, Psi_new, L/Lr/Psi update, next M partials ----------------
__global__ __launch_bounds__(512) void k_upd(float* __restrict__ ws, float* __restrict__ dout, int pass) {
    __shared__ float szi[64][68];
    __shared__ float lt[64][66];
    const int t = threadIdx.x, b = blockIdx.x;
    const int p0 = 64 * b;
    const int pl = t >> 3, oct = t & 7;
    const int p = p0 + pl;

    if (pass == 8) {
        float4 v0 = *(const float4*)&ws[WS_L + p * 64 + oct * 8];
        float4 v1 = *(const float4*)&ws[WS_L + p * 64 + oct * 8 + 4];
        *(float4*)&dout[p * 64 + oct * 8] = v0;
        *(float4*)&dout[p * 64 + oct * 8 + 4] = v1;
        if (oct == 0) dout[32768 + p] = ws[WS_PSI + p];
        return;
    }

    #pragma unroll
    for (int q = 0; q < 8; q++) { int o = t + 512 * q; szi[o >> 6][o & 63] = ws[WS_SZI + o]; }
    #pragma unroll
    for (int q = 0; q < 8; q++) { int o = t + 512 * q; lt[o >> 6][o & 63] = ws[WS_LT + (o >> 6) * 512 + p0 + (o & 63)]; }
    __syncthreads();

    float acc[8] = {0.f, 0.f, 0.f, 0.f, 0.f, 0.f, 0.f, 0.f};
    #pragma unroll
    for (int j = 0; j < 64; j++) {
        float ltv = lt[j][pl];
        float4 s0 = *(const float4*)&szi[j][oct * 8];
        float4 s1 = *(const float4*)&szi[j][oct * 8 + 4];
        acc[0] = fmaf(ltv, s0.x, acc[0]); acc[1] = fmaf(ltv, s0.y, acc[1]);
        acc[2] = fmaf(ltv, s0.z, acc[2]); acc[3] = fmaf(ltv, s0.w, acc[3]);
        acc[4] = fmaf(ltv, s1.x, acc[4]); acc[5] = fmaf(ltv, s1.y, acc[5]);
        acc[6] = fmaf(ltv, s1.z, acc[6]); acc[7] = fmaf(ltv, s1.w, acc[7]);
    }
    float psum = 0.f;
    #pragma unroll
    for (int i = 0; i < 8; i++) psum = fmaf(acc[i], lt[oct * 8 + i][pl], psum);
    psum += __shfl_xor(psum, 1);
    psum += __shfl_xor(psum, 2);
    psum += __shfl_xor(psum, 4);
    float psin = (ws[WS_YY + p] - psum) * (1.f / (float)NN);

    float4 a0 = make_float4(acc[0], acc[1], acc[2], acc[3]);
    float4 a1 = make_float4(acc[4], acc[5], acc[6], acc[7]);
    *(float4*)&ws[WS_L + p * 64 + oct * 8] = a0;
    *(float4*)&ws[WS_L + p * 64 + oct * 8 + 4] = a1;
    #pragma unroll
    for (int i = 0; i < 8; i++) ws[WS_LR + (oct * 8 + i) * 512 + p] = acc[i];
    if (oct == 0) ws[WS_PSI + p] = psin;

    float rs = rsqrtf(fmaxf(psin, 1e-8f));
    __syncthreads();
    #pragma unroll
    for (int i = 0; i < 8; i++) szi[pl][oct * 8 + i] = rs * acc[i];
    __syncthreads();
    partial_M(szi, t, ws + WS_MPART + b * 4096);
}

extern "C" void kernel_launch(void* const* d_in, const int* in_sizes, int n_in,
                              void* d_out, int out_size, void* d_ws, size_t ws_size,
                              hipStream_t stream) {
    const float* y  = (const float*)d_in[0];
    const float* l1 = (const float*)d_in[1];
    const float* l2 = (const float*)d_in[2];
    const float* p1 = (const float*)d_in[3];
    const float* p2 = (const float*)d_in[4];
    float* out = (float*)d_out;
    float* ws  = (float*)d_ws;

    if (ws_size < WS_TOTAL_F * sizeof(float)) return;

    k_init<<<130, 256, 0, stream>>>(l1, l2, p1, p2, ws);
    k_syrk<<<3 * NSLICE, 512, 0, stream>>>(y, ws);
    k_syy_reduce<<<1024, 256, 0, stream>>>(ws);
    k_m0<<<8, 512, 0, stream>>>(ws);
    for (int pass = 0; pass <= 8; pass++) {
        k_pre<<<1, 512, 0, stream>>>(ws);
        k_mid1<<<8, 512, 0, stream>>>(ws);
        k_post<<<1, 512, 0, stream>>>(ws, out, pass);
        k_upd<<<8, 512, 0, stream>>>(ws, out, pass);
    }
}